// Round 14
// baseline (67.638 us; speedup 1.0000x reference)
//
#include <hip/hip_runtime.h>
#include <cmath>

#define LSEQ   1024
#define NPROJ  4620
#define NPADW  4736
#define DINNER 1536
#define NH     12
#define HDIM   128
#define OFF_Z  0
#define OFF_X  1536
#define OFF_B  3072
#define OFF_C  3840
#define OFF_DT 4608

typedef unsigned short u16;
typedef unsigned int u32;
typedef short bf16x8 __attribute__((ext_vector_type(8)));
typedef float f32x4 __attribute__((ext_vector_type(4)));

__device__ inline u16 f2b(float f) {            // f32 -> bf16 RNE
  unsigned u = __float_as_uint(f);
  return (u16)((u + 0x7fffu + ((u >> 16) & 1u)) >> 16);
}
__device__ inline float b2f(u16 h) { return __uint_as_float(((unsigned)h) << 16); }
__device__ inline u32 pk2(float a, float b) { return (u32)f2b(a) | ((u32)f2b(b) << 16); }

__device__ inline void gll16(const void* g, void* l) {
  __builtin_amdgcn_global_load_lds((const __attribute__((address_space(1))) void*)g,
                                   (__attribute__((address_space(3))) void*)l, 16, 0, 0);
}

// ---------- split to single bf16 planes: x -> Ah, W_in -> Wh (padded) ----------
#define S0N 196608              // 1024*768/4
#define S1N 909312              // 4736*768/4 (valid 887040)
#define S1V 887040
#define S2N 294912              // 768*1536/4 (done in chunk_scan)
__global__ __launch_bounds__(256) void ksplit_all(const float* __restrict__ x,
    const float* __restrict__ Wi, u16* __restrict__ Ah, u16* __restrict__ Wh) {
  int i = blockIdx.x * 256 + threadIdx.x;
  const float* src; u16* hi; int j, valid;
  if (i < S0N) { src = x;  hi = Ah; j = i;       valid = S0N; }
  else         { src = Wi; hi = Wh; j = i - S0N; valid = S1V; }
  float4 v = (j < valid) ? ((const float4*)src)[j] : make_float4(0.f, 0.f, 0.f, 0.f);
  ((uint2*)hi)[j] = make_uint2(pk2(v.x, v.y), pk2(v.z, v.w));
}

// ---------- pure-bf16 MFMA GEMM, R5 skeleton, BK=128 (two k-halves in LDS) ----------
template<int BM, int BN, int MAP, bool NG>
__global__ __launch_bounds__(256) void gemm1(const u16* __restrict__ Ah,
    const u16* __restrict__ Wh, float* __restrict__ C,
    int lda, int ldw, int Ksl, int Nreal, int ldc) {
  constexpr int HALF = (BM + BN) * 64;          // u16 per k-half (A then W)
  constexpr int IA = BM / 8, IH = IA + BN / 8;  // gll16 per half
  constexpr int FRn = BN / 32;
  __shared__ u16 lds[2 * HALF];
  const int tid = threadIdx.x;
  const int l = tid & 63, w = tid >> 6;
  const int wm = w >> 1, wn = w & 1;
  const int kg = l >> 4, li = l & 15;

  int b = blockIdx.x, m0, n0, koff;
  float* Cp = C;
  if (MAP == 0) {                 // in-proj: 8 xcd * (10 colblk(64) x 16 rowblk(64))
    int xcd = b & 7, idx = b >> 3;
    m0 = (idx & 15) * 64;
    n0 = (xcd * 10 + (idx >> 4)) * 64;
    koff = 0;
    if (NG && n0 >= NPADW) return;
  } else {                        // out-proj: split-K=4; 8 xcd * (6 grp x 16 rowblk)
    int xcd = b & 7, idx = b >> 3;
    int gg = xcd * 6 + (idx >> 4);
    m0 = (idx & 15) * 64;
    n0 = (gg % 12) * 64;
    koff = (gg / 12) * 384;
    Cp = C + (size_t)(gg / 12) * LSEQ * ldc;
  }

  const int srcg = ((l & 7) ^ (l >> 3)) * 8;
  auto stage = [&](int t) {
    const int k0 = koff + t * 128;
#pragma unroll
    for (int kk = 0; kk < 2; ++kk)
      for (int q = w; q < IH; q += 4) {
        const u16* gb; int r0b, ldk, dst;
        if (q < IA) { gb = Ah; r0b = m0 + 8 * q;        dst = kk * HALF + 8 * q * 64;              ldk = lda; }
        else        { gb = Wh; r0b = n0 + 8 * (q - IA); dst = kk * HALF + BM * 64 + 8 * (q - IA) * 64; ldk = ldw; }
        gll16(gb + (size_t)(r0b + (l >> 3)) * ldk + k0 + kk * 64 + srcg, &lds[dst]);
      }
  };
  auto rd = [&](int kk, int region, int row, int ks) -> bf16x8 {
    return *(const bf16x8*)&lds[kk * HALF + region + row * 64 + (((ks * 4 + kg) ^ (row & 7)) << 3)];
  };

  f32x4 acc[2][FRn];
#pragma unroll
  for (int m = 0; m < 2; ++m)
#pragma unroll
    for (int n = 0; n < FRn; ++n) acc[m][n] = (f32x4){0.f, 0.f, 0.f, 0.f};

  const int NT = Ksl / 128;
  stage(0);
  asm volatile("s_waitcnt vmcnt(0)" ::: "memory");
  __syncthreads();
  for (int t = 0; t < NT; ++t) {
    bf16x8 a0[2][2], w0[FRn][2], a1[2][2], w1[FRn][2];
#pragma unroll
    for (int ks = 0; ks < 2; ++ks) {
#pragma unroll
      for (int m = 0; m < 2; ++m) {
        a0[m][ks] = rd(0, 0, wm * 32 + m * 16 + li, ks);
        a1[m][ks] = rd(1, 0, wm * 32 + m * 16 + li, ks);
      }
#pragma unroll
      for (int n = 0; n < FRn; ++n) {
        w0[n][ks] = rd(0, BM * 64, wn * (BN / 2) + n * 16 + li, ks);
        w1[n][ks] = rd(1, BM * 64, wn * (BN / 2) + n * 16 + li, ks);
      }
    }
    // MFMA on k-half 0 (ds_reads for half 1 still in flight; barrier drains lgkm)
#pragma unroll
    for (int ks = 0; ks < 2; ++ks)
#pragma unroll
      for (int m = 0; m < 2; ++m)
#pragma unroll
        for (int n = 0; n < FRn; ++n)
          acc[m][n] = __builtin_amdgcn_mfma_f32_16x16x32_bf16(a0[m][ks], w0[n][ks], acc[m][n], 0, 0, 0);
    __syncthreads();                    // all waves done reading LDS (lgkm drained)
    if (t + 1 < NT) stage(t + 1);       // loads fly under the half-1 MFMA block
#pragma unroll
    for (int ks = 0; ks < 2; ++ks)
#pragma unroll
      for (int m = 0; m < 2; ++m)
#pragma unroll
        for (int n = 0; n < FRn; ++n)
          acc[m][n] = __builtin_amdgcn_mfma_f32_16x16x32_bf16(a1[m][ks], w1[n][ks], acc[m][n], 0, 0, 0);
    if (t + 1 < NT) {
      asm volatile("s_waitcnt vmcnt(0)" ::: "memory");
      __syncthreads();
    }
  }
#pragma unroll
  for (int m = 0; m < 2; ++m) {
    int rbase = m0 + wm * 32 + m * 16 + kg * 4;
#pragma unroll
    for (int n = 0; n < FRn; ++n) {
      int col = n0 + wn * (BN / 2) + n * 16 + li;
      if (!NG || col < Nreal) {
#pragma unroll
        for (int r = 0; r < 4; ++r)
          Cp[(size_t)(rbase + r) * ldc + col] = acc[m][n][r];
      }
    }
  }
}

// ---------------- out = rms[t] * (P0+P1+P2+P3) ----------------
__global__ __launch_bounds__(256) void addk(const float* __restrict__ P,
    const float* __restrict__ rmsacc, float* __restrict__ out) {
  const int S = LSEQ * 768 / 4;
  int i = blockIdx.x * 256 + threadIdx.x;
  int t = i / 192;                        // 192 float4 per output row
  float rms = rsqrtf(rmsacc[t] * (1.f / 1536.f) + 1e-5f);
  float4 a = ((const float4*)P)[i];
  float4 b = ((const float4*)P)[i + S];
  float4 c = ((const float4*)P)[i + 2 * S];
  float4 d = ((const float4*)P)[i + 3 * S];
  ((float4*)out)[i] = make_float4((a.x + b.x + c.x + d.x) * rms,
                                  (a.y + b.y + c.y + d.y) * rms,
                                  (a.z + b.z + c.z + d.z) * rms,
                                  (a.w + b.w + c.w + d.w) * rms);
}

// -------- fused: inline dt/Phi scan + conv1d+SiLU + chunk-state via MFMA --------
// Sloc written directly as bf16 (chunk-local states; scanned in place later).
__global__ __launch_bounds__(256) void conv_state(const float* __restrict__ proj,
    const float* __restrict__ cw, const float* __restrict__ cb,
    const float* __restrict__ A_log, const float* __restrict__ dt_bias,
    u16* __restrict__ xactT, u16* __restrict__ Sloc,
    float* __restrict__ Phi, float* __restrict__ dts, float* __restrict__ rmsacc) {
  const int k = blockIdx.x, h = blockIdx.y, tid = threadIdx.x;
  const int l = tid & 63, w = tid >> 6, kg = l >> 4, li = l & 15;
  __shared__ u16 Bw[4096];
  __shared__ u16 Xt[8192];
  __shared__ float wS[64];
  __shared__ float wsum[4];
  __shared__ float phiC[64], dtC[64];
  const int s0 = k * 64;

  if (h == 0 && tid < 64) rmsacc[k * 64 + tid] = 0.f;
  // ---- inline dt/Phi: full-head scan, write own chunk ----
  {
    float Ac = -expf(A_log[h]);
    float bb = dt_bias[h];
    float v[4], s = 0.f;
#pragma unroll
    for (int u = 0; u < 4; ++u) {
      int t = tid * 4 + u;
      float xr = proj[(size_t)t * NPROJ + OFF_DT + h];
      float sp = (xr > 20.f) ? xr : log1pf(expf(xr));
      v[u] = sp + bb;
      s += v[u];
    }
    int lane = tid & 63, wv = tid >> 6;
    float ps = s;
#pragma unroll
    for (int d = 1; d < 64; d <<= 1) {
      float o = __shfl_up(ps, d);
      if (lane >= d) ps += o;
    }
    if (lane == 63) wsum[wv] = ps;
    __syncthreads();
    float off = 0.f;
    for (int q = 0; q < wv; ++q) off += wsum[q];
    float run = off + ps - s;
#pragma unroll
    for (int u = 0; u < 4; ++u) {
      int t = tid * 4 + u;
      run += v[u];
      if ((t >> 6) == k) {
        float ph = Ac * run;
        phiC[t & 63] = ph;
        dtC[t & 63] = v[u];
        Phi[t * NH + h] = ph;
        dts[t * NH + h] = v[u];
      }
    }
  }
  __syncthreads();
  if (tid < 64) wS[tid] = expf(phiC[63] + fminf(-phiC[tid], 80.f)) * dtC[tid];
  __syncthreads();
  // ---- Bw[d][s] = wS[s] * B[s][d]  (swizzled bf16) ----
#pragma unroll
  for (int u = 0; u < 4; ++u) {
    int idx = tid + u * 256, s = idx >> 4, q = (idx & 15) * 4;
    float4 v = *(const float4*)(proj + (size_t)(s0 + s) * NPROJ + OFF_B + h * 64 + q);
    float ws_ = wS[s];
    float vv[4] = {v.x, v.y, v.z, v.w};
#pragma unroll
    for (int j = 0; j < 4; ++j) {
      int d = q + j;
      Bw[d * 64 + (((s >> 3) ^ (d & 7)) << 3) + (s & 7)] = f2b(vv[j] * ws_);
    }
  }
  // ---- conv + silu -> Xt (swizzled LDS) + xactT (linear global) ----
  {
    int c = tid & 127, th = tid >> 7;
    int cg = h * HDIM + c;
    float w0 = cw[cg * 4], w1 = cw[cg * 4 + 1], w2 = cw[cg * 4 + 2], w3 = cw[cg * 4 + 3];
    float bias = cb[cg];
    int tb = s0 + th * 32;
    auto P = [&](int t) { return (t >= 0) ? proj[(size_t)t * NPROJ + OFF_X + cg] : 0.f; };
    float x0 = P(tb - 3), x1 = P(tb - 2), x2 = P(tb - 1);
    u32 pkb[16];
    float prev = 0.f;
#pragma unroll
    for (int i = 0; i < 32; ++i) {
      float x3 = P(tb + i);
      float a = bias;
      a = fmaf(x0, w0, a); a = fmaf(x1, w1, a); a = fmaf(x2, w2, a); a = fmaf(x3, w3, a);
      float sv = a / (1.f + expf(-a));
      if (i & 1) pkb[i >> 1] = pk2(prev, sv); else prev = sv;
      x0 = x1; x1 = x2; x2 = x3;
    }
#pragma unroll
    for (int g = 0; g < 4; ++g) {
      int sg = th * 4 + g;
      *(uint4*)&Xt[c * 64 + ((sg ^ (c & 7)) << 3)] =
          make_uint4(pkb[g * 4], pkb[g * 4 + 1], pkb[g * 4 + 2], pkb[g * 4 + 3]);
    }
    size_t xo = ((size_t)(k * NH + h) * 128 + c) * 64 + th * 32;
#pragma unroll
    for (int g = 0; g < 4; ++g)
      *(uint4*)(xactT + xo + g * 8) =
          make_uint4(pkb[g * 4], pkb[g * 4 + 1], pkb[g * 4 + 2], pkb[g * 4 + 3]);
  }
  __syncthreads();
  // ---- H^T[c][d] = sum_s Xt[c][s] * Bw[d][s] ----
  const int wm = w >> 1, wn = w & 1;
  auto rd = [&](const u16* reg, int row, int ks) -> bf16x8 {
    return *(const bf16x8*)&reg[row * 64 + (((ks * 4 + kg) ^ (row & 7)) << 3)];
  };
  f32x4 acc[4][2];
#pragma unroll
  for (int m = 0; m < 4; ++m)
#pragma unroll
    for (int n = 0; n < 2; ++n) acc[m][n] = (f32x4){0.f, 0.f, 0.f, 0.f};
#pragma unroll
  for (int ks = 0; ks < 2; ++ks) {
    bf16x8 xf[4], bf[2];
#pragma unroll
    for (int m = 0; m < 4; ++m) xf[m] = rd(Xt, wm * 64 + m * 16 + li, ks);
#pragma unroll
    for (int n = 0; n < 2; ++n) bf[n] = rd(Bw, wn * 32 + n * 16 + li, ks);
#pragma unroll
    for (int m = 0; m < 4; ++m)
#pragma unroll
      for (int n = 0; n < 2; ++n)
        acc[m][n] = __builtin_amdgcn_mfma_f32_16x16x32_bf16(xf[m], bf[n], acc[m][n], 0, 0, 0);
  }
  u16* dst = Sloc + (((size_t)(k * NH + h)) << 13);
#pragma unroll
  for (int m = 0; m < 4; ++m)
#pragma unroll
    for (int n = 0; n < 2; ++n)
#pragma unroll
      for (int r = 0; r < 4; ++r) {
        int c = wm * 64 + m * 16 + kg * 4 + r;
        int d = wn * 32 + n * 16 + li;
        dst[c * 64 + d] = f2b(acc[m][n][r]);
      }
}

// ------- in-place chunk scan (bf16 states, f32 accumulate) + W_out bf16 conversion -------
__global__ __launch_bounds__(256) void chunk_scan(u16* __restrict__ Sloc,
    const float* __restrict__ Phi, const float* __restrict__ Wo, u16* __restrict__ Woh) {
  int gi = blockIdx.x * 256 + threadIdx.x;
#pragma unroll
  for (int it = 0; it < 3; ++it) {          // 384*256*3 = S2N exactly
    int j = gi + it * 98304;
    float4 vv = ((const float4*)Wo)[j];
    ((uint2*)Woh)[j] = make_uint2(pk2(vv.x, vv.y), pk2(vv.z, vv.w));
  }
  int b = blockIdx.x;
  int h = b >> 5;
  int e = (b & 31) * 256 + threadIdx.x;
  float run = b2f(Sloc[((size_t)h << 13) + e]);
#pragma unroll
  for (int k = 1; k < 16; ++k) {
    float lam = expf(Phi[(k * 64 + 63) * NH + h] - Phi[(k * 64 - 1) * NH + h]);
    size_t o = ((size_t)(k * NH + h) << 13) + e;
    run = fmaf(lam, run, b2f(Sloc[o]));
    Sloc[o] = f2b(run);
  }
}

// ------- per-chunk output + fused gate: Yh = y*nw*silu(z); rmsacc += Σ y² -------
__global__ __launch_bounds__(256) void ssm_out(const float* __restrict__ proj,
    const u16* __restrict__ xactT, const float* __restrict__ Phi,
    const float* __restrict__ dts, const float* __restrict__ Dp,
    const u16* __restrict__ Sloc, const float* __restrict__ nw,
    u16* __restrict__ Yh, float* __restrict__ rmsacc) {
  const int k = blockIdx.x, h = blockIdx.y, zh = blockIdx.z, tid = threadIdx.x;
  const int l = tid & 63, w = tid >> 6, kg = l >> 4, li = l & 15;
  const int wm = w >> 1, wn = w & 1;
  __shared__ u16 Cs[4096], Bs[4096], Ps[4096], Xs[4096], Ss[4096];
  __shared__ float phiT[64], eSs[64], dSs[64], eTs[64];
  __shared__ float sq[64], nws[64];
  const int t0 = k * 64;
  const int srcg = ((l & 7) ^ (l >> 3)) * 8;
  {
#pragma unroll
    for (int j = 0; j < 2; ++j) {
      int rb = w * 16 + j * 8;
      gll16(xactT + ((size_t)(k * NH + h) * 128 + zh * 64 + rb + (l >> 3)) * 64 + srcg, &Xs[rb * 64]);
    }
    if (k > 0) {
      const u16* ssrc = Sloc + (((size_t)((k - 1) * NH + h) * 128 + zh * 64)) * 64;
#pragma unroll
      for (int j = 0; j < 2; ++j) {
        int rb = w * 16 + j * 8;
        gll16(ssrc + (size_t)(rb + (l >> 3)) * 64 + srcg, &Ss[rb * 64]);
      }
    }
  }
#pragma unroll
  for (int u = 0; u < 4; ++u) {
    int idx = tid + u * 256, i = idx >> 4, q = (idx & 15) * 4;
    int aoff = i * 64 + (((q >> 3) ^ (i & 7)) << 3) + (q & 4);
    float4 cv = *(const float4*)(proj + (size_t)(t0 + i) * NPROJ + OFF_C + h * 64 + q);
    float4 bv = *(const float4*)(proj + (size_t)(t0 + i) * NPROJ + OFF_B + h * 64 + q);
    *(uint2*)&Cs[aoff] = make_uint2(pk2(cv.x, cv.y), pk2(cv.z, cv.w));
    *(uint2*)&Bs[aoff] = make_uint2(pk2(bv.x, bv.y), pk2(bv.z, bv.w));
  }
  if (tid < 64) {
    float p = Phi[(t0 + tid) * NH + h];
    phiT[tid] = p;
    eSs[tid] = fminf(-p, 80.f);
    dSs[tid] = dts[(t0 + tid) * NH + h];
    eTs[tid] = (k > 0) ? expf(p - Phi[(t0 - 1) * NH + h]) : 0.f;
    sq[tid] = 0.f;
    nws[tid] = nw[h * HDIM + zh * 64 + tid];
  }
  __syncthreads();
  auto rd = [&](const u16* reg, int row, int ks) -> bf16x8 {
    return *(const bf16x8*)&reg[row * 64 + (((ks * 4 + kg) ^ (row & 7)) << 3)];
  };
  bf16x8 Cf[2][2];
  f32x4 accS[2][2];
#pragma unroll
  for (int m = 0; m < 2; ++m)
#pragma unroll
    for (int n = 0; n < 2; ++n) accS[m][n] = (f32x4){0.f, 0.f, 0.f, 0.f};
#pragma unroll
  for (int ks = 0; ks < 2; ++ks) {
    bf16x8 Bf[2];
#pragma unroll
    for (int m = 0; m < 2; ++m) Cf[m][ks] = rd(Cs, wm * 32 + m * 16 + li, ks);
#pragma unroll
    for (int n = 0; n < 2; ++n) Bf[n] = rd(Bs, wn * 32 + n * 16 + li, ks);
#pragma unroll
    for (int m = 0; m < 2; ++m)
#pragma unroll
      for (int n = 0; n < 2; ++n)
        accS[m][n] = __builtin_amdgcn_mfma_f32_16x16x32_bf16(Cf[m][ks], Bf[n], accS[m][n], 0, 0, 0);
  }
#pragma unroll
  for (int m = 0; m < 2; ++m)
#pragma unroll
    for (int n = 0; n < 2; ++n)
#pragma unroll
      for (int r = 0; r < 4; ++r) {
        int t = wm * 32 + m * 16 + kg * 4 + r;
        int s = wn * 32 + n * 16 + li;
        float f = (s <= t) ? expf(phiT[t] + eSs[s]) * dSs[s] : 0.f;
        Ps[t * 64 + (((s >> 3) ^ (t & 7)) << 3) + (s & 7)] = f2b(accS[m][n][r] * f);
      }
  __syncthreads();
  f32x4 accY[2][2], acc2[2][2];
#pragma unroll
  for (int m = 0; m < 2; ++m)
#pragma unroll
    for (int n = 0; n < 2; ++n) {
      accY[m][n] = (f32x4){0.f, 0.f, 0.f, 0.f};
      acc2[m][n] = (f32x4){0.f, 0.f, 0.f, 0.f};
    }
#pragma unroll
  for (int ks = 0; ks < 2; ++ks) {
    bf16x8 Pf[2], Xf[2];
#pragma unroll
    for (int m = 0; m < 2; ++m) Pf[m] = rd(Ps, wm * 32 + m * 16 + li, ks);
#pragma unroll
    for (int n = 0; n < 2; ++n) Xf[n] = rd(Xs, wn * 32 + n * 16 + li, ks);
#pragma unroll
    for (int m = 0; m < 2; ++m)
#pragma unroll
      for (int n = 0; n < 2; ++n)
        accY[m][n] = __builtin_amdgcn_mfma_f32_16x16x32_bf16(Pf[m], Xf[n], accY[m][n], 0, 0, 0);
    if (k > 0) {
      bf16x8 Sf[2];
#pragma unroll
      for (int n = 0; n < 2; ++n) Sf[n] = rd(Ss, wn * 32 + n * 16 + li, ks);
#pragma unroll
      for (int m = 0; m < 2; ++m)
#pragma unroll
        for (int n = 0; n < 2; ++n)
          acc2[m][n] = __builtin_amdgcn_mfma_f32_16x16x32_bf16(Cf[m][ks], Sf[n], acc2[m][n], 0, 0, 0);
    }
  }
  float dp = Dp[h];
  float ls[8] = {};
#pragma unroll
  for (int m = 0; m < 2; ++m)
#pragma unroll
    for (int n = 0; n < 2; ++n)
#pragma unroll
      for (int r = 0; r < 4; ++r) {
        int t = wm * 32 + m * 16 + kg * 4 + r;
        int c = wn * 32 + n * 16 + li;
        float xv = b2f(Xs[c * 64 + (((t >> 3) ^ (c & 7)) << 3) + (t & 7)]);
        float val = accY[m][n][r] + eTs[t] * acc2[m][n][r] + dp * xv;
        ls[m * 4 + r] = fmaf(val, val, ls[m * 4 + r]);
        float z = proj[(size_t)(t0 + t) * NPROJ + OFF_Z + h * HDIM + zh * 64 + c];
        float sz = z / (1.f + expf(-z));
        Yh[(size_t)(t0 + t) * DINNER + h * HDIM + zh * 64 + c] = f2b(val * nws[c] * sz);
      }
#pragma unroll
  for (int j = 0; j < 8; ++j) {
    float v = ls[j];
    v += __shfl_xor(v, 1); v += __shfl_xor(v, 2);
    v += __shfl_xor(v, 4); v += __shfl_xor(v, 8);
    if (li == 0) atomicAdd(&sq[wm * 32 + (j >> 2) * 16 + kg * 4 + (j & 3)], v);
  }
  __syncthreads();
  if (tid < 64) atomicAdd(&rmsacc[t0 + tid], sq[tid]);
}

extern "C" void kernel_launch(void* const* d_in, const int* in_sizes, int n_in,
                              void* d_out, int out_size, void* d_ws, size_t ws_size,
                              hipStream_t stream) {
  const float* x       = (const float*)d_in[0];
  const float* W_in    = (const float*)d_in[1];
  const float* conv_w  = (const float*)d_in[2];
  const float* conv_b  = (const float*)d_in[3];
  const float* A_log   = (const float*)d_in[4];
  const float* Dp      = (const float*)d_in[5];
  const float* dt_bias = (const float*)d_in[6];
  const float* W_out   = (const float*)d_in[7];
  const float* norm_w  = (const float*)d_in[8];
  float* out = (float*)d_out;

  char* base = (char*)d_ws;
  size_t o = 0;
  auto alloc = [&](size_t bytes) { char* r = base + o; o += (bytes + 255) & ~(size_t)255; return r; };
  float* proj   = (float*)alloc((size_t)LSEQ * NPROJ * 4);
  float* Phi    = (float*)alloc((size_t)LSEQ * NH * 4);
  float* dts    = (float*)alloc((size_t)LSEQ * NH * 4);
  float* rmsacc = (float*)alloc((size_t)LSEQ * 4);
  u16*   Sloc   = (u16*)alloc((size_t)16 * NH * 8192 * 2);
  u16*   xactT  = (u16*)alloc((size_t)16 * NH * 8192 * 2);
  u16*   Ah     = (u16*)alloc((size_t)LSEQ * 768 * 2);
  u16*   Wh     = (u16*)alloc((size_t)NPADW * 768 * 2);
  u16*   Woh    = (u16*)alloc((size_t)768 * DINNER * 2);
  u16*   Yh     = (u16*)alloc((size_t)LSEQ * DINNER * 2);
  float* Pp     = (float*)alloc((size_t)4 * LSEQ * 768 * 4);

  ksplit_all<<<dim3((S0N + S1N) / 256), 256, 0, stream>>>(x, W_in, Ah, Wh);
  gemm1<64, 64, 0, true><<<dim3(1280), 256, 0, stream>>>(
      Ah, Wh, proj, 768, 768, 768, NPROJ, NPROJ);
  conv_state<<<dim3(16, NH), 256, 0, stream>>>(
      proj, conv_w, conv_b, A_log, dt_bias, xactT, Sloc, Phi, dts, rmsacc);
  chunk_scan<<<dim3(NH * 32), 256, 0, stream>>>(Sloc, Phi, W_out, Woh);
  ssm_out<<<dim3(16, NH, 2), 256, 0, stream>>>(
      proj, xactT, Phi, dts, Dp, Sloc, norm_w, Yh, rmsacc);
  gemm1<64, 64, 1, false><<<dim3(768), 256, 0, stream>>>(
      Yh, Woh, Pp, 1536, 1536, 384, 768, 768);
  addk<<<dim3(LSEQ * 768 / 4 / 256), 256, 0, stream>>>(Pp, rmsacc, out);
}

// Round 15
// 67.457 us; speedup vs baseline: 1.0027x; 1.0027x over previous
//
#include <hip/hip_runtime.h>
#include <cmath>

#define LSEQ   1024
#define NPROJ  4620
#define NPADW  4736
#define DINNER 1536
#define NH     12
#define HDIM   128
#define OFF_Z  0
#define OFF_X  1536
#define OFF_B  3072
#define OFF_C  3840
#define OFF_DT 4608

typedef unsigned short u16;
typedef unsigned int u32;
typedef short bf16x8 __attribute__((ext_vector_type(8)));
typedef float f32x4 __attribute__((ext_vector_type(4)));

__device__ inline u16 f2b(float f) {            // f32 -> bf16 RNE
  unsigned u = __float_as_uint(f);
  return (u16)((u + 0x7fffu + ((u >> 16) & 1u)) >> 16);
}
__device__ inline float b2f(u16 h) { return __uint_as_float(((unsigned)h) << 16); }
__device__ inline u32 pk2(float a, float b) { return (u32)f2b(a) | ((u32)f2b(b) << 16); }

__device__ inline void gll16(const void* g, void* l) {
  __builtin_amdgcn_global_load_lds((const __attribute__((address_space(1))) void*)g,
                                   (__attribute__((address_space(3))) void*)l, 16, 0, 0);
}

// ---------- split to single bf16 planes: x -> Ah, W_in -> Wh (padded) ----------
#define S0N 196608              // 1024*768/4
#define S1N 909312              // 4736*768/4 (valid 887040)
#define S1V 887040
#define S2N 294912              // 768*1536/4 (done in chunk_scan)
__global__ __launch_bounds__(256) void ksplit_all(const float* __restrict__ x,
    const float* __restrict__ Wi, u16* __restrict__ Ah, u16* __restrict__ Wh) {
  int i = blockIdx.x * 256 + threadIdx.x;
  const float* src; u16* hi; int j, valid;
  if (i < S0N) { src = x;  hi = Ah; j = i;       valid = S0N; }
  else         { src = Wi; hi = Wh; j = i - S0N; valid = S1V; }
  float4 v = (j < valid) ? ((const float4*)src)[j] : make_float4(0.f, 0.f, 0.f, 0.f);
  ((uint2*)hi)[j] = make_uint2(pk2(v.x, v.y), pk2(v.z, v.w));
}

// ---------- pure-bf16 MFMA GEMM, R5 skeleton, BK=128 (two k-halves in LDS) ----------
template<int BM, int BN, int MAP, bool NG>
__global__ __launch_bounds__(256) void gemm1(const u16* __restrict__ Ah,
    const u16* __restrict__ Wh, float* __restrict__ C,
    int lda, int ldw, int Ksl, int Nreal, int ldc) {
  constexpr int HALF = (BM + BN) * 64;          // u16 per k-half (A then W)
  constexpr int IA = BM / 8, IH = IA + BN / 8;  // gll16 per half
  constexpr int FRn = BN / 32;
  __shared__ u16 lds[2 * HALF];
  const int tid = threadIdx.x;
  const int l = tid & 63, w = tid >> 6;
  const int wm = w >> 1, wn = w & 1;
  const int kg = l >> 4, li = l & 15;

  int b = blockIdx.x, m0, n0, koff;
  float* Cp = C;
  if (MAP == 0) {                 // in-proj: 8 xcd * (5 colblk(128) x 16 rowblk(64))
    int xcd = b & 7, idx = b >> 3;
    m0 = (idx & 15) * 64;
    n0 = (xcd * 5 + (idx >> 4)) * 128;
    koff = 0;
    if (NG && n0 >= NPADW) return;
  } else {                        // out-proj: split-K=2; 8 xcd * (3 grp x 16 rowblk)
    int xcd = b & 7, idx = b >> 3;
    int gg = xcd * 3 + (idx >> 4);              // 0..23 = (n 0..11, kslice 0..1)
    m0 = (idx & 15) * 64;
    n0 = (gg % 12) * 64;
    koff = (gg / 12) * 768;
    Cp = C + (size_t)(gg / 12) * LSEQ * ldc;
  }

  const int srcg = ((l & 7) ^ (l >> 3)) * 8;
  auto stage = [&](int t) {
    const int k0 = koff + t * 128;
#pragma unroll
    for (int kk = 0; kk < 2; ++kk)
      for (int q = w; q < IH; q += 4) {
        const u16* gb; int r0b, ldk, dst;
        if (q < IA) { gb = Ah; r0b = m0 + 8 * q;        dst = kk * HALF + 8 * q * 64;              ldk = lda; }
        else        { gb = Wh; r0b = n0 + 8 * (q - IA); dst = kk * HALF + BM * 64 + 8 * (q - IA) * 64; ldk = ldw; }
        gll16(gb + (size_t)(r0b + (l >> 3)) * ldk + k0 + kk * 64 + srcg, &lds[dst]);
      }
  };
  auto rd = [&](int kk, int region, int row, int ks) -> bf16x8 {
    return *(const bf16x8*)&lds[kk * HALF + region + row * 64 + (((ks * 4 + kg) ^ (row & 7)) << 3)];
  };

  f32x4 acc[2][FRn];
#pragma unroll
  for (int m = 0; m < 2; ++m)
#pragma unroll
    for (int n = 0; n < FRn; ++n) acc[m][n] = (f32x4){0.f, 0.f, 0.f, 0.f};

  const int NT = Ksl / 128;
  stage(0);
  asm volatile("s_waitcnt vmcnt(0)" ::: "memory");
  __syncthreads();
  for (int t = 0; t < NT; ++t) {
    bf16x8 a0[2][2], w0[FRn][2], a1[2][2], w1[FRn][2];
#pragma unroll
    for (int ks = 0; ks < 2; ++ks) {
#pragma unroll
      for (int m = 0; m < 2; ++m) {
        a0[m][ks] = rd(0, 0, wm * 32 + m * 16 + li, ks);
        a1[m][ks] = rd(1, 0, wm * 32 + m * 16 + li, ks);
      }
#pragma unroll
      for (int n = 0; n < FRn; ++n) {
        w0[n][ks] = rd(0, BM * 64, wn * (BN / 2) + n * 16 + li, ks);
        w1[n][ks] = rd(1, BM * 64, wn * (BN / 2) + n * 16 + li, ks);
      }
    }
    // MFMA on k-half 0
#pragma unroll
    for (int ks = 0; ks < 2; ++ks)
#pragma unroll
      for (int m = 0; m < 2; ++m)
#pragma unroll
        for (int n = 0; n < FRn; ++n)
          acc[m][n] = __builtin_amdgcn_mfma_f32_16x16x32_bf16(a0[m][ks], w0[n][ks], acc[m][n], 0, 0, 0);
    __syncthreads();                    // all waves done reading LDS (lgkm drained)
    if (t + 1 < NT) stage(t + 1);       // loads fly under the half-1 MFMA block
#pragma unroll
    for (int ks = 0; ks < 2; ++ks)
#pragma unroll
      for (int m = 0; m < 2; ++m)
#pragma unroll
        for (int n = 0; n < FRn; ++n)
          acc[m][n] = __builtin_amdgcn_mfma_f32_16x16x32_bf16(a1[m][ks], w1[n][ks], acc[m][n], 0, 0, 0);
    if (t + 1 < NT) {
      asm volatile("s_waitcnt vmcnt(0)" ::: "memory");
      __syncthreads();
    }
  }
#pragma unroll
  for (int m = 0; m < 2; ++m) {
    int rbase = m0 + wm * 32 + m * 16 + kg * 4;
#pragma unroll
    for (int n = 0; n < FRn; ++n) {
      int col = n0 + wn * (BN / 2) + n * 16 + li;
      if (!NG || col < Nreal) {
#pragma unroll
        for (int r = 0; r < 4; ++r)
          Cp[(size_t)(rbase + r) * ldc + col] = acc[m][n][r];
      }
    }
  }
}

// ---------------- out = rms[t] * (P0+P1) ----------------
__global__ __launch_bounds__(256) void addk(const float* __restrict__ P,
    const float* __restrict__ rmsacc, float* __restrict__ out) {
  const int S = LSEQ * 768 / 4;
  int i = blockIdx.x * 256 + threadIdx.x;
  int t = i / 192;                        // 192 float4 per output row
  float rms = rsqrtf(rmsacc[t] * (1.f / 1536.f) + 1e-5f);
  float4 a = ((const float4*)P)[i];
  float4 b = ((const float4*)P)[i + S];
  ((float4*)out)[i] = make_float4((a.x + b.x) * rms, (a.y + b.y) * rms,
                                  (a.z + b.z) * rms, (a.w + b.w) * rms);
}

// -------- fused: inline dt/Phi scan + conv1d+SiLU + chunk-state via MFMA --------
__global__ __launch_bounds__(256) void conv_state(const float* __restrict__ proj,
    const float* __restrict__ cw, const float* __restrict__ cb,
    const float* __restrict__ A_log, const float* __restrict__ dt_bias,
    u16* __restrict__ xactT, u16* __restrict__ Sloc,
    float* __restrict__ Phi, float* __restrict__ dts, float* __restrict__ rmsacc) {
  const int k = blockIdx.x, h = blockIdx.y, tid = threadIdx.x;
  const int l = tid & 63, w = tid >> 6, kg = l >> 4, li = l & 15;
  __shared__ u16 Bw[4096];
  __shared__ u16 Xt[8192];
  __shared__ float wS[64];
  __shared__ float wsum[4];
  __shared__ float phiC[64], dtC[64];
  const int s0 = k * 64;

  if (h == 0 && tid < 64) rmsacc[k * 64 + tid] = 0.f;
  // ---- inline dt/Phi: full-head scan, write own chunk ----
  {
    float Ac = -expf(A_log[h]);
    float bb = dt_bias[h];
    float v[4], s = 0.f;
#pragma unroll
    for (int u = 0; u < 4; ++u) {
      int t = tid * 4 + u;
      float xr = proj[(size_t)t * NPROJ + OFF_DT + h];
      float sp = (xr > 20.f) ? xr : log1pf(expf(xr));
      v[u] = sp + bb;
      s += v[u];
    }
    int lane = tid & 63, wv = tid >> 6;
    float ps = s;
#pragma unroll
    for (int d = 1; d < 64; d <<= 1) {
      float o = __shfl_up(ps, d);
      if (lane >= d) ps += o;
    }
    if (lane == 63) wsum[wv] = ps;
    __syncthreads();
    float off = 0.f;
    for (int q = 0; q < wv; ++q) off += wsum[q];
    float run = off + ps - s;
#pragma unroll
    for (int u = 0; u < 4; ++u) {
      int t = tid * 4 + u;
      run += v[u];
      if ((t >> 6) == k) {
        float ph = Ac * run;
        phiC[t & 63] = ph;
        dtC[t & 63] = v[u];
        Phi[t * NH + h] = ph;
        dts[t * NH + h] = v[u];
      }
    }
  }
  __syncthreads();
  if (tid < 64) wS[tid] = expf(phiC[63] + fminf(-phiC[tid], 80.f)) * dtC[tid];
  __syncthreads();
  // ---- Bw[d][s] = wS[s] * B[s][d]  (swizzled bf16) ----
#pragma unroll
  for (int u = 0; u < 4; ++u) {
    int idx = tid + u * 256, s = idx >> 4, q = (idx & 15) * 4;
    float4 v = *(const float4*)(proj + (size_t)(s0 + s) * NPROJ + OFF_B + h * 64 + q);
    float ws_ = wS[s];
    float vv[4] = {v.x, v.y, v.z, v.w};
#pragma unroll
    for (int j = 0; j < 4; ++j) {
      int d = q + j;
      Bw[d * 64 + (((s >> 3) ^ (d & 7)) << 3) + (s & 7)] = f2b(vv[j] * ws_);
    }
  }
  // ---- conv + silu -> Xt (swizzled LDS) + xactT (linear global) ----
  {
    int c = tid & 127, th = tid >> 7;
    int cg = h * HDIM + c;
    float w0 = cw[cg * 4], w1 = cw[cg * 4 + 1], w2 = cw[cg * 4 + 2], w3 = cw[cg * 4 + 3];
    float bias = cb[cg];
    int tb = s0 + th * 32;
    auto P = [&](int t) { return (t >= 0) ? proj[(size_t)t * NPROJ + OFF_X + cg] : 0.f; };
    float x0 = P(tb - 3), x1 = P(tb - 2), x2 = P(tb - 1);
    u32 pkb[16];
    float prev = 0.f;
#pragma unroll
    for (int i = 0; i < 32; ++i) {
      float x3 = P(tb + i);
      float a = bias;
      a = fmaf(x0, w0, a); a = fmaf(x1, w1, a); a = fmaf(x2, w2, a); a = fmaf(x3, w3, a);
      float sv = a / (1.f + expf(-a));
      if (i & 1) pkb[i >> 1] = pk2(prev, sv); else prev = sv;
      x0 = x1; x1 = x2; x2 = x3;
    }
#pragma unroll
    for (int g = 0; g < 4; ++g) {
      int sg = th * 4 + g;
      *(uint4*)&Xt[c * 64 + ((sg ^ (c & 7)) << 3)] =
          make_uint4(pkb[g * 4], pkb[g * 4 + 1], pkb[g * 4 + 2], pkb[g * 4 + 3]);
    }
    size_t xo = ((size_t)(k * NH + h) * 128 + c) * 64 + th * 32;
#pragma unroll
    for (int g = 0; g < 4; ++g)
      *(uint4*)(xactT + xo + g * 8) =
          make_uint4(pkb[g * 4], pkb[g * 4 + 1], pkb[g * 4 + 2], pkb[g * 4 + 3]);
  }
  __syncthreads();
  // ---- H^T[c][d] = sum_s Xt[c][s] * Bw[d][s] ----
  const int wm = w >> 1, wn = w & 1;
  auto rd = [&](const u16* reg, int row, int ks) -> bf16x8 {
    return *(const bf16x8*)&reg[row * 64 + (((ks * 4 + kg) ^ (row & 7)) << 3)];
  };
  f32x4 acc[4][2];
#pragma unroll
  for (int m = 0; m < 4; ++m)
#pragma unroll
    for (int n = 0; n < 2; ++n) acc[m][n] = (f32x4){0.f, 0.f, 0.f, 0.f};
#pragma unroll
  for (int ks = 0; ks < 2; ++ks) {
    bf16x8 xf[4], bf[2];
#pragma unroll
    for (int m = 0; m < 4; ++m) xf[m] = rd(Xt, wm * 64 + m * 16 + li, ks);
#pragma unroll
    for (int n = 0; n < 2; ++n) bf[n] = rd(Bw, wn * 32 + n * 16 + li, ks);
#pragma unroll
    for (int m = 0; m < 4; ++m)
#pragma unroll
      for (int n = 0; n < 2; ++n)
        acc[m][n] = __builtin_amdgcn_mfma_f32_16x16x32_bf16(xf[m], bf[n], acc[m][n], 0, 0, 0);
  }
  u16* dst = Sloc + (((size_t)(k * NH + h)) << 13);
#pragma unroll
  for (int m = 0; m < 4; ++m)
#pragma unroll
    for (int n = 0; n < 2; ++n)
#pragma unroll
      for (int r = 0; r < 4; ++r) {
        int c = wm * 64 + m * 16 + kg * 4 + r;
        int d = wn * 32 + n * 16 + li;
        dst[c * 64 + d] = f2b(acc[m][n][r]);
      }
}

// ------- in-place chunk scan (bf16 states, f32 accumulate) + W_out bf16 conversion -------
__global__ __launch_bounds__(256) void chunk_scan(u16* __restrict__ Sloc,
    const float* __restrict__ Phi, const float* __restrict__ Wo, u16* __restrict__ Woh) {
  int gi = blockIdx.x * 256 + threadIdx.x;
#pragma unroll
  for (int it = 0; it < 3; ++it) {          // 384*256*3 = S2N exactly
    int j = gi + it * 98304;
    float4 vv = ((const float4*)Wo)[j];
    ((uint2*)Woh)[j] = make_uint2(pk2(vv.x, vv.y), pk2(vv.z, vv.w));
  }
  int b = blockIdx.x;
  int h = b >> 5;
  int e = (b & 31) * 256 + threadIdx.x;
  float run = b2f(Sloc[((size_t)h << 13) + e]);
#pragma unroll
  for (int k = 1; k < 16; ++k) {
    float lam = expf(Phi[(k * 64 + 63) * NH + h] - Phi[(k * 64 - 1) * NH + h]);
    size_t o = ((size_t)(k * NH + h) << 13) + e;
    run = fmaf(lam, run, b2f(Sloc[o]));
    Sloc[o] = f2b(run);
  }
}

// ------- per-chunk output + fused gate: Yh = y*nw*silu(z); rmsacc += Σ y² -------
__global__ __launch_bounds__(256) void ssm_out(const float* __restrict__ proj,
    const u16* __restrict__ xactT, const float* __restrict__ Phi,
    const float* __restrict__ dts, const float* __restrict__ Dp,
    const u16* __restrict__ Sloc, const float* __restrict__ nw,
    u16* __restrict__ Yh, float* __restrict__ rmsacc) {
  const int k = blockIdx.x, h = blockIdx.y, zh = blockIdx.z, tid = threadIdx.x;
  const int l = tid & 63, w = tid >> 6, kg = l >> 4, li = l & 15;
  const int wm = w >> 1, wn = w & 1;
  __shared__ u16 Cs[4096], Bs[4096], Ps[4096], Xs[4096], Ss[4096];
  __shared__ float phiT[64], eSs[64], dSs[64], eTs[64];
  __shared__ float sq[64], nws[64];
  const int t0 = k * 64;
  const int srcg = ((l & 7) ^ (l >> 3)) * 8;
  {
#pragma unroll
    for (int j = 0; j < 2; ++j) {
      int rb = w * 16 + j * 8;
      gll16(xactT + ((size_t)(k * NH + h) * 128 + zh * 64 + rb + (l >> 3)) * 64 + srcg, &Xs[rb * 64]);
    }
    if (k > 0) {
      const u16* ssrc = Sloc + (((size_t)((k - 1) * NH + h) * 128 + zh * 64)) * 64;
#pragma unroll
      for (int j = 0; j < 2; ++j) {
        int rb = w * 16 + j * 8;
        gll16(ssrc + (size_t)(rb + (l >> 3)) * 64 + srcg, &Ss[rb * 64]);
      }
    }
  }
#pragma unroll
  for (int u = 0; u < 4; ++u) {
    int idx = tid + u * 256, i = idx >> 4, q = (idx & 15) * 4;
    int aoff = i * 64 + (((q >> 3) ^ (i & 7)) << 3) + (q & 4);
    float4 cv = *(const float4*)(proj + (size_t)(t0 + i) * NPROJ + OFF_C + h * 64 + q);
    float4 bv = *(const float4*)(proj + (size_t)(t0 + i) * NPROJ + OFF_B + h * 64 + q);
    *(uint2*)&Cs[aoff] = make_uint2(pk2(cv.x, cv.y), pk2(cv.z, cv.w));
    *(uint2*)&Bs[aoff] = make_uint2(pk2(bv.x, bv.y), pk2(bv.z, bv.w));
  }
  if (tid < 64) {
    float p = Phi[(t0 + tid) * NH + h];
    phiT[tid] = p;
    eSs[tid] = fminf(-p, 80.f);
    dSs[tid] = dts[(t0 + tid) * NH + h];
    eTs[tid] = (k > 0) ? expf(p - Phi[(t0 - 1) * NH + h]) : 0.f;
    sq[tid] = 0.f;
    nws[tid] = nw[h * HDIM + zh * 64 + tid];
  }
  __syncthreads();
  auto rd = [&](const u16* reg, int row, int ks) -> bf16x8 {
    return *(const bf16x8*)&reg[row * 64 + (((ks * 4 + kg) ^ (row & 7)) << 3)];
  };
  bf16x8 Cf[2][2];
  f32x4 accS[2][2];
#pragma unroll
  for (int m = 0; m < 2; ++m)
#pragma unroll
    for (int n = 0; n < 2; ++n) accS[m][n] = (f32x4){0.f, 0.f, 0.f, 0.f};
#pragma unroll
  for (int ks = 0; ks < 2; ++ks) {
    bf16x8 Bf[2];
#pragma unroll
    for (int m = 0; m < 2; ++m) Cf[m][ks] = rd(Cs, wm * 32 + m * 16 + li, ks);
#pragma unroll
    for (int n = 0; n < 2; ++n) Bf[n] = rd(Bs, wn * 32 + n * 16 + li, ks);
#pragma unroll
    for (int m = 0; m < 2; ++m)
#pragma unroll
      for (int n = 0; n < 2; ++n)
        accS[m][n] = __builtin_amdgcn_mfma_f32_16x16x32_bf16(Cf[m][ks], Bf[n], accS[m][n], 0, 0, 0);
  }
#pragma unroll
  for (int m = 0; m < 2; ++m)
#pragma unroll
    for (int n = 0; n < 2; ++n)
#pragma unroll
      for (int r = 0; r < 4; ++r) {
        int t = wm * 32 + m * 16 + kg * 4 + r;
        int s = wn * 32 + n * 16 + li;
        float f = (s <= t) ? expf(phiT[t] + eSs[s]) * dSs[s] : 0.f;
        Ps[t * 64 + (((s >> 3) ^ (t & 7)) << 3) + (s & 7)] = f2b(accS[m][n][r] * f);
      }
  __syncthreads();
  f32x4 accY[2][2], acc2[2][2];
#pragma unroll
  for (int m = 0; m < 2; ++m)
#pragma unroll
    for (int n = 0; n < 2; ++n) {
      accY[m][n] = (f32x4){0.f, 0.f, 0.f, 0.f};
      acc2[m][n] = (f32x4){0.f, 0.f, 0.f, 0.f};
    }
#pragma unroll
  for (int ks = 0; ks < 2; ++ks) {
    bf16x8 Pf[2], Xf[2];
#pragma unroll
    for (int m = 0; m < 2; ++m) Pf[m] = rd(Ps, wm * 32 + m * 16 + li, ks);
#pragma unroll
    for (int n = 0; n < 2; ++n) Xf[n] = rd(Xs, wn * 32 + n * 16 + li, ks);
#pragma unroll
    for (int m = 0; m < 2; ++m)
#pragma unroll
      for (int n = 0; n < 2; ++n)
        accY[m][n] = __builtin_amdgcn_mfma_f32_16x16x32_bf16(Pf[m], Xf[n], accY[m][n], 0, 0, 0);
    if (k > 0) {
      bf16x8 Sf[2];
#pragma unroll
      for (int n = 0; n < 2; ++n) Sf[n] = rd(Ss, wn * 32 + n * 16 + li, ks);
#pragma unroll
      for (int m = 0; m < 2; ++m)
#pragma unroll
        for (int n = 0; n < 2; ++n)
          acc2[m][n] = __builtin_amdgcn_mfma_f32_16x16x32_bf16(Cf[m][ks], Sf[n], acc2[m][n], 0, 0, 0);
    }
  }
  float dp = Dp[h];
  float ls[8] = {};
#pragma unroll
  for (int m = 0; m < 2; ++m)
#pragma unroll
    for (int n = 0; n < 2; ++n)
#pragma unroll
      for (int r = 0; r < 4; ++r) {
        int t = wm * 32 + m * 16 + kg * 4 + r;
        int c = wn * 32 + n * 16 + li;
        float xv = b2f(Xs[c * 64 + (((t >> 3) ^ (c & 7)) << 3) + (t & 7)]);
        float val = accY[m][n][r] + eTs[t] * acc2[m][n][r] + dp * xv;
        ls[m * 4 + r] = fmaf(val, val, ls[m * 4 + r]);
        float z = proj[(size_t)(t0 + t) * NPROJ + OFF_Z + h * HDIM + zh * 64 + c];
        float sz = z / (1.f + expf(-z));
        Yh[(size_t)(t0 + t) * DINNER + h * HDIM + zh * 64 + c] = f2b(val * nws[c] * sz);
      }
#pragma unroll
  for (int j = 0; j < 8; ++j) {
    float v = ls[j];
    v += __shfl_xor(v, 1); v += __shfl_xor(v, 2);
    v += __shfl_xor(v, 4); v += __shfl_xor(v, 8);
    if (li == 0) atomicAdd(&sq[wm * 32 + (j >> 2) * 16 + kg * 4 + (j & 3)], v);
  }
  __syncthreads();
  if (tid < 64) atomicAdd(&rmsacc[t0 + tid], sq[tid]);
}

extern "C" void kernel_launch(void* const* d_in, const int* in_sizes, int n_in,
                              void* d_out, int out_size, void* d_ws, size_t ws_size,
                              hipStream_t stream) {
  const float* x       = (const float*)d_in[0];
  const float* W_in    = (const float*)d_in[1];
  const float* conv_w  = (const float*)d_in[2];
  const float* conv_b  = (const float*)d_in[3];
  const float* A_log   = (const float*)d_in[4];
  const float* Dp      = (const float*)d_in[5];
  const float* dt_bias = (const float*)d_in[6];
  const float* W_out   = (const float*)d_in[7];
  const float* norm_w  = (const float*)d_in[8];
  float* out = (float*)d_out;

  char* base = (char*)d_ws;
  size_t o = 0;
  auto alloc = [&](size_t bytes) { char* r = base + o; o += (bytes + 255) & ~(size_t)255; return r; };
  float* proj   = (float*)alloc((size_t)LSEQ * NPROJ * 4);
  float* Phi    = (float*)alloc((size_t)LSEQ * NH * 4);
  float* dts    = (float*)alloc((size_t)LSEQ * NH * 4);
  float* rmsacc = (float*)alloc((size_t)LSEQ * 4);
  u16*   Sloc   = (u16*)alloc((size_t)16 * NH * 8192 * 2);
  u16*   xactT  = (u16*)alloc((size_t)16 * NH * 8192 * 2);
  u16*   Ah     = (u16*)alloc((size_t)LSEQ * 768 * 2);
  u16*   Wh     = (u16*)alloc((size_t)NPADW * 768 * 2);
  u16*   Woh    = (u16*)alloc((size_t)768 * DINNER * 2);
  u16*   Yh     = (u16*)alloc((size_t)LSEQ * DINNER * 2);
  float* Pp     = (float*)alloc((size_t)2 * LSEQ * 768 * 4);

  ksplit_all<<<dim3((S0N + S1N) / 256), 256, 0, stream>>>(x, W_in, Ah, Wh);
  gemm1<64, 128, 0, true><<<dim3(640), 256, 0, stream>>>(
      Ah, Wh, proj, 768, 768, 768, NPROJ, NPROJ);
  conv_state<<<dim3(16, NH), 256, 0, stream>>>(
      proj, conv_w, conv_b, A_log, dt_bias, xactT, Sloc, Phi, dts, rmsacc);
  chunk_scan<<<dim3(NH * 32), 256, 0, stream>>>(Sloc, Phi, W_out, Woh);
  ssm_out<<<dim3(16, NH, 2), 256, 0, stream>>>(
      proj, xactT, Phi, dts, Dp, Sloc, norm_w, Yh, rmsacc);
  gemm1<64, 64, 1, false><<<dim3(384), 256, 0, stream>>>(
      Yh, Woh, Pp, 1536, 1536, 768, 768, 768);
  addk<<<dim3(LSEQ * 768 / 4 / 256), 256, 0, stream>>>(Pp, rmsacc, out);
}

// Round 16
// 66.329 us; speedup vs baseline: 1.0197x; 1.0170x over previous
//
#include <hip/hip_runtime.h>
#include <cmath>

#define LSEQ   1024
#define NPROJ  4620
#define NPADW  4736
#define DINNER 1536
#define NH     12
#define HDIM   128
#define OFF_Z  0
#define OFF_X  1536
#define OFF_B  3072
#define OFF_C  3840
#define OFF_DT 4608

typedef unsigned short u16;
typedef unsigned int u32;
typedef short bf16x8 __attribute__((ext_vector_type(8)));
typedef float f32x4 __attribute__((ext_vector_type(4)));

__device__ inline u16 f2b(float f) {            // f32 -> bf16 RNE
  unsigned u = __float_as_uint(f);
  return (u16)((u + 0x7fffu + ((u >> 16) & 1u)) >> 16);
}
__device__ inline float b2f(u16 h) { return __uint_as_float(((unsigned)h) << 16); }
__device__ inline u32 pk2(float a, float b) { return (u32)f2b(a) | ((u32)f2b(b) << 16); }

__device__ inline void gll16(const void* g, void* l) {
  __builtin_amdgcn_global_load_lds((const __attribute__((address_space(1))) void*)g,
                                   (__attribute__((address_space(3))) void*)l, 16, 0, 0);
}

// ---------- split to single bf16 planes: x -> Ah, W_in -> Wh (padded) ----------
#define S0N 196608              // 1024*768/4
#define S1N 909312              // 4736*768/4 (valid 887040)
#define S1V 887040
#define S2N 294912              // 768*1536/4 (done in chunk_scan)
__global__ __launch_bounds__(256) void ksplit_all(const float* __restrict__ x,
    const float* __restrict__ Wi, u16* __restrict__ Ah, u16* __restrict__ Wh) {
  int i = blockIdx.x * 256 + threadIdx.x;
  const float* src; u16* hi; int j, valid;
  if (i < S0N) { src = x;  hi = Ah; j = i;       valid = S0N; }
  else         { src = Wi; hi = Wh; j = i - S0N; valid = S1V; }
  float4 v = (j < valid) ? ((const float4*)src)[j] : make_float4(0.f, 0.f, 0.f, 0.f);
  ((uint2*)hi)[j] = make_uint2(pk2(v.x, v.y), pk2(v.z, v.w));
}

// ---------- pure-bf16 MFMA GEMM, R5 skeleton, BK=128 (two k-halves in LDS) ----------
template<int BM, int BN, int MAP, bool NG>
__global__ __launch_bounds__(256) void gemm1(const u16* __restrict__ Ah,
    const u16* __restrict__ Wh, float* __restrict__ C,
    int lda, int ldw, int Ksl, int Nreal, int ldc) {
  constexpr int HALF = (BM + BN) * 64;          // u16 per k-half (A then W)
  constexpr int IA = BM / 8, IH = IA + BN / 8;  // gll16 per half
  constexpr int FRn = BN / 32;
  __shared__ u16 lds[2 * HALF];
  const int tid = threadIdx.x;
  const int l = tid & 63, w = tid >> 6;
  const int wm = w >> 1, wn = w & 1;
  const int kg = l >> 4, li = l & 15;

  int b = blockIdx.x, m0, n0, koff;
  float* Cp = C;
  if (MAP == 0) {                 // in-proj: 8 xcd * (5 colblk(128) x 16 rowblk(64))
    int xcd = b & 7, idx = b >> 3;
    m0 = (idx & 15) * 64;
    n0 = (xcd * 5 + (idx >> 4)) * 128;
    koff = 0;
    if (NG && n0 >= NPADW) return;
  } else {                        // out-proj: split-K=4; 8 xcd * (6 grp x 16 rowblk)
    int xcd = b & 7, idx = b >> 3;
    int gg = xcd * 6 + (idx >> 4);
    m0 = (idx & 15) * 64;
    n0 = (gg % 12) * 64;
    koff = (gg / 12) * 384;
    Cp = C + (size_t)(gg / 12) * LSEQ * ldc;
  }

  const int srcg = ((l & 7) ^ (l >> 3)) * 8;
  auto stage = [&](int t) {
    const int k0 = koff + t * 128;
#pragma unroll
    for (int kk = 0; kk < 2; ++kk)
      for (int q = w; q < IH; q += 4) {
        const u16* gb; int r0b, ldk, dst;
        if (q < IA) { gb = Ah; r0b = m0 + 8 * q;        dst = kk * HALF + 8 * q * 64;              ldk = lda; }
        else        { gb = Wh; r0b = n0 + 8 * (q - IA); dst = kk * HALF + BM * 64 + 8 * (q - IA) * 64; ldk = ldw; }
        gll16(gb + (size_t)(r0b + (l >> 3)) * ldk + k0 + kk * 64 + srcg, &lds[dst]);
      }
  };
  auto rd = [&](int kk, int region, int row, int ks) -> bf16x8 {
    return *(const bf16x8*)&lds[kk * HALF + region + row * 64 + (((ks * 4 + kg) ^ (row & 7)) << 3)];
  };

  f32x4 acc[2][FRn];
#pragma unroll
  for (int m = 0; m < 2; ++m)
#pragma unroll
    for (int n = 0; n < FRn; ++n) acc[m][n] = (f32x4){0.f, 0.f, 0.f, 0.f};

  const int NT = Ksl / 128;
  stage(0);
  asm volatile("s_waitcnt vmcnt(0)" ::: "memory");
  __syncthreads();
  for (int t = 0; t < NT; ++t) {
    bf16x8 a0[2][2], w0[FRn][2], a1[2][2], w1[FRn][2];
#pragma unroll
    for (int ks = 0; ks < 2; ++ks) {
#pragma unroll
      for (int m = 0; m < 2; ++m) {
        a0[m][ks] = rd(0, 0, wm * 32 + m * 16 + li, ks);
        a1[m][ks] = rd(1, 0, wm * 32 + m * 16 + li, ks);
      }
#pragma unroll
      for (int n = 0; n < FRn; ++n) {
        w0[n][ks] = rd(0, BM * 64, wn * (BN / 2) + n * 16 + li, ks);
        w1[n][ks] = rd(1, BM * 64, wn * (BN / 2) + n * 16 + li, ks);
      }
    }
    // MFMA on k-half 0 (ds_reads for half 1 still in flight; barrier drains lgkm)
#pragma unroll
    for (int ks = 0; ks < 2; ++ks)
#pragma unroll
      for (int m = 0; m < 2; ++m)
#pragma unroll
        for (int n = 0; n < FRn; ++n)
          acc[m][n] = __builtin_amdgcn_mfma_f32_16x16x32_bf16(a0[m][ks], w0[n][ks], acc[m][n], 0, 0, 0);
    __syncthreads();                    // all waves done reading LDS (lgkm drained)
    if (t + 1 < NT) stage(t + 1);       // loads fly under the half-1 MFMA block
#pragma unroll
    for (int ks = 0; ks < 2; ++ks)
#pragma unroll
      for (int m = 0; m < 2; ++m)
#pragma unroll
        for (int n = 0; n < FRn; ++n)
          acc[m][n] = __builtin_amdgcn_mfma_f32_16x16x32_bf16(a1[m][ks], w1[n][ks], acc[m][n], 0, 0, 0);
    if (t + 1 < NT) {
      asm volatile("s_waitcnt vmcnt(0)" ::: "memory");
      __syncthreads();
    }
  }
#pragma unroll
  for (int m = 0; m < 2; ++m) {
    int rbase = m0 + wm * 32 + m * 16 + kg * 4;
#pragma unroll
    for (int n = 0; n < FRn; ++n) {
      int col = n0 + wn * (BN / 2) + n * 16 + li;
      if (!NG || col < Nreal) {
#pragma unroll
        for (int r = 0; r < 4; ++r)
          Cp[(size_t)(rbase + r) * ldc + col] = acc[m][n][r];
      }
    }
  }
}

// ---------------- out = rms[t] * (P0+P1+P2+P3) ----------------
__global__ __launch_bounds__(256) void addk(const float* __restrict__ P,
    const float* __restrict__ rmsacc, float* __restrict__ out) {
  const int S = LSEQ * 768 / 4;
  int i = blockIdx.x * 256 + threadIdx.x;
  int t = i / 192;                        // 192 float4 per output row
  float rms = rsqrtf(rmsacc[t] * (1.f / 1536.f) + 1e-5f);
  float4 a = ((const float4*)P)[i];
  float4 b = ((const float4*)P)[i + S];
  float4 c = ((const float4*)P)[i + 2 * S];
  float4 d = ((const float4*)P)[i + 3 * S];
  ((float4*)out)[i] = make_float4((a.x + b.x + c.x + d.x) * rms,
                                  (a.y + b.y + c.y + d.y) * rms,
                                  (a.z + b.z + c.z + d.z) * rms,
                                  (a.w + b.w + c.w + d.w) * rms);
}

// -------- fused: inline dt/Phi scan + conv1d+SiLU + chunk-state via MFMA --------
// Sloc written directly as bf16 (chunk-local states; scanned in place later).
__global__ __launch_bounds__(256) void conv_state(const float* __restrict__ proj,
    const float* __restrict__ cw, const float* __restrict__ cb,
    const float* __restrict__ A_log, const float* __restrict__ dt_bias,
    u16* __restrict__ xactT, u16* __restrict__ Sloc,
    float* __restrict__ Phi, float* __restrict__ dts, float* __restrict__ rmsacc) {
  const int k = blockIdx.x, h = blockIdx.y, tid = threadIdx.x;
  const int l = tid & 63, w = tid >> 6, kg = l >> 4, li = l & 15;
  __shared__ u16 Bw[4096];
  __shared__ u16 Xt[8192];
  __shared__ float wS[64];
  __shared__ float wsum[4];
  __shared__ float phiC[64], dtC[64];
  const int s0 = k * 64;

  if (h == 0 && tid < 64) rmsacc[k * 64 + tid] = 0.f;
  // ---- inline dt/Phi: full-head scan, write own chunk ----
  {
    float Ac = -expf(A_log[h]);
    float bb = dt_bias[h];
    float v[4], s = 0.f;
#pragma unroll
    for (int u = 0; u < 4; ++u) {
      int t = tid * 4 + u;
      float xr = proj[(size_t)t * NPROJ + OFF_DT + h];
      float sp = (xr > 20.f) ? xr : log1pf(expf(xr));
      v[u] = sp + bb;
      s += v[u];
    }
    int lane = tid & 63, wv = tid >> 6;
    float ps = s;
#pragma unroll
    for (int d = 1; d < 64; d <<= 1) {
      float o = __shfl_up(ps, d);
      if (lane >= d) ps += o;
    }
    if (lane == 63) wsum[wv] = ps;
    __syncthreads();
    float off = 0.f;
    for (int q = 0; q < wv; ++q) off += wsum[q];
    float run = off + ps - s;
#pragma unroll
    for (int u = 0; u < 4; ++u) {
      int t = tid * 4 + u;
      run += v[u];
      if ((t >> 6) == k) {
        float ph = Ac * run;
        phiC[t & 63] = ph;
        dtC[t & 63] = v[u];
        Phi[t * NH + h] = ph;
        dts[t * NH + h] = v[u];
      }
    }
  }
  __syncthreads();
  if (tid < 64) wS[tid] = expf(phiC[63] + fminf(-phiC[tid], 80.f)) * dtC[tid];
  __syncthreads();
  // ---- Bw[d][s] = wS[s] * B[s][d]  (swizzled bf16) ----
#pragma unroll
  for (int u = 0; u < 4; ++u) {
    int idx = tid + u * 256, s = idx >> 4, q = (idx & 15) * 4;
    float4 v = *(const float4*)(proj + (size_t)(s0 + s) * NPROJ + OFF_B + h * 64 + q);
    float ws_ = wS[s];
    float vv[4] = {v.x, v.y, v.z, v.w};
#pragma unroll
    for (int j = 0; j < 4; ++j) {
      int d = q + j;
      Bw[d * 64 + (((s >> 3) ^ (d & 7)) << 3) + (s & 7)] = f2b(vv[j] * ws_);
    }
  }
  // ---- conv + silu -> Xt (swizzled LDS) + xactT (linear global) ----
  {
    int c = tid & 127, th = tid >> 7;
    int cg = h * HDIM + c;
    float w0 = cw[cg * 4], w1 = cw[cg * 4 + 1], w2 = cw[cg * 4 + 2], w3 = cw[cg * 4 + 3];
    float bias = cb[cg];
    int tb = s0 + th * 32;
    auto P = [&](int t) { return (t >= 0) ? proj[(size_t)t * NPROJ + OFF_X + cg] : 0.f; };
    float x0 = P(tb - 3), x1 = P(tb - 2), x2 = P(tb - 1);
    u32 pkb[16];
    float prev = 0.f;
#pragma unroll
    for (int i = 0; i < 32; ++i) {
      float x3 = P(tb + i);
      float a = bias;
      a = fmaf(x0, w0, a); a = fmaf(x1, w1, a); a = fmaf(x2, w2, a); a = fmaf(x3, w3, a);
      float sv = a / (1.f + expf(-a));
      if (i & 1) pkb[i >> 1] = pk2(prev, sv); else prev = sv;
      x0 = x1; x1 = x2; x2 = x3;
    }
#pragma unroll
    for (int g = 0; g < 4; ++g) {
      int sg = th * 4 + g;
      *(uint4*)&Xt[c * 64 + ((sg ^ (c & 7)) << 3)] =
          make_uint4(pkb[g * 4], pkb[g * 4 + 1], pkb[g * 4 + 2], pkb[g * 4 + 3]);
    }
    size_t xo = ((size_t)(k * NH + h) * 128 + c) * 64 + th * 32;
#pragma unroll
    for (int g = 0; g < 4; ++g)
      *(uint4*)(xactT + xo + g * 8) =
          make_uint4(pkb[g * 4], pkb[g * 4 + 1], pkb[g * 4 + 2], pkb[g * 4 + 3]);
  }
  __syncthreads();
  // ---- H^T[c][d] = sum_s Xt[c][s] * Bw[d][s] ----
  const int wm = w >> 1, wn = w & 1;
  auto rd = [&](const u16* reg, int row, int ks) -> bf16x8 {
    return *(const bf16x8*)&reg[row * 64 + (((ks * 4 + kg) ^ (row & 7)) << 3)];
  };
  f32x4 acc[4][2];
#pragma unroll
  for (int m = 0; m < 4; ++m)
#pragma unroll
    for (int n = 0; n < 2; ++n) acc[m][n] = (f32x4){0.f, 0.f, 0.f, 0.f};
#pragma unroll
  for (int ks = 0; ks < 2; ++ks) {
    bf16x8 xf[4], bf[2];
#pragma unroll
    for (int m = 0; m < 4; ++m) xf[m] = rd(Xt, wm * 64 + m * 16 + li, ks);
#pragma unroll
    for (int n = 0; n < 2; ++n) bf[n] = rd(Bw, wn * 32 + n * 16 + li, ks);
#pragma unroll
    for (int m = 0; m < 4; ++m)
#pragma unroll
      for (int n = 0; n < 2; ++n)
        acc[m][n] = __builtin_amdgcn_mfma_f32_16x16x32_bf16(xf[m], bf[n], acc[m][n], 0, 0, 0);
  }
  u16* dst = Sloc + (((size_t)(k * NH + h)) << 13);
#pragma unroll
  for (int m = 0; m < 4; ++m)
#pragma unroll
    for (int n = 0; n < 2; ++n)
#pragma unroll
      for (int r = 0; r < 4; ++r) {
        int c = wm * 64 + m * 16 + kg * 4 + r;
        int d = wn * 32 + n * 16 + li;
        dst[c * 64 + d] = f2b(acc[m][n][r]);
      }
}

// ------- in-place chunk scan (bf16 states, f32 accumulate) + W_out bf16 conversion -------
__global__ __launch_bounds__(256) void chunk_scan(u16* __restrict__ Sloc,
    const float* __restrict__ Phi, const float* __restrict__ Wo, u16* __restrict__ Woh) {
  int gi = blockIdx.x * 256 + threadIdx.x;
#pragma unroll
  for (int it = 0; it < 3; ++it) {          // 384*256*3 = S2N exactly
    int j = gi + it * 98304;
    float4 vv = ((const float4*)Wo)[j];
    ((uint2*)Woh)[j] = make_uint2(pk2(vv.x, vv.y), pk2(vv.z, vv.w));
  }
  int b = blockIdx.x;
  int h = b >> 5;
  int e = (b & 31) * 256 + threadIdx.x;
  float run = b2f(Sloc[((size_t)h << 13) + e]);
#pragma unroll
  for (int k = 1; k < 16; ++k) {
    float lam = expf(Phi[(k * 64 + 63) * NH + h] - Phi[(k * 64 - 1) * NH + h]);
    size_t o = ((size_t)(k * NH + h) << 13) + e;
    run = fmaf(lam, run, b2f(Sloc[o]));
    Sloc[o] = f2b(run);
  }
}

// ------- per-chunk output + fused gate: Yh = y*nw*silu(z); rmsacc += Σ y² -------
__global__ __launch_bounds__(256) void ssm_out(const float* __restrict__ proj,
    const u16* __restrict__ xactT, const float* __restrict__ Phi,
    const float* __restrict__ dts, const float* __restrict__ Dp,
    const u16* __restrict__ Sloc, const float* __restrict__ nw,
    u16* __restrict__ Yh, float* __restrict__ rmsacc) {
  const int k = blockIdx.x, h = blockIdx.y, zh = blockIdx.z, tid = threadIdx.x;
  const int l = tid & 63, w = tid >> 6, kg = l >> 4, li = l & 15;
  const int wm = w >> 1, wn = w & 1;
  __shared__ u16 Cs[4096], Bs[4096], Ps[4096], Xs[4096], Ss[4096];
  __shared__ float phiT[64], eSs[64], dSs[64], eTs[64];
  __shared__ float sq[64], nws[64];
  const int t0 = k * 64;
  const int srcg = ((l & 7) ^ (l >> 3)) * 8;
  {
#pragma unroll
    for (int j = 0; j < 2; ++j) {
      int rb = w * 16 + j * 8;
      gll16(xactT + ((size_t)(k * NH + h) * 128 + zh * 64 + rb + (l >> 3)) * 64 + srcg, &Xs[rb * 64]);
    }
    if (k > 0) {
      const u16* ssrc = Sloc + (((size_t)((k - 1) * NH + h) * 128 + zh * 64)) * 64;
#pragma unroll
      for (int j = 0; j < 2; ++j) {
        int rb = w * 16 + j * 8;
        gll16(ssrc + (size_t)(rb + (l >> 3)) * 64 + srcg, &Ss[rb * 64]);
      }
    }
  }
#pragma unroll
  for (int u = 0; u < 4; ++u) {
    int idx = tid + u * 256, i = idx >> 4, q = (idx & 15) * 4;
    int aoff = i * 64 + (((q >> 3) ^ (i & 7)) << 3) + (q & 4);
    float4 cv = *(const float4*)(proj + (size_t)(t0 + i) * NPROJ + OFF_C + h * 64 + q);
    float4 bv = *(const float4*)(proj + (size_t)(t0 + i) * NPROJ + OFF_B + h * 64 + q);
    *(uint2*)&Cs[aoff] = make_uint2(pk2(cv.x, cv.y), pk2(cv.z, cv.w));
    *(uint2*)&Bs[aoff] = make_uint2(pk2(bv.x, bv.y), pk2(bv.z, bv.w));
  }
  if (tid < 64) {
    float p = Phi[(t0 + tid) * NH + h];
    phiT[tid] = p;
    eSs[tid] = fminf(-p, 80.f);
    dSs[tid] = dts[(t0 + tid) * NH + h];
    eTs[tid] = (k > 0) ? expf(p - Phi[(t0 - 1) * NH + h]) : 0.f;
    sq[tid] = 0.f;
    nws[tid] = nw[h * HDIM + zh * 64 + tid];
  }
  __syncthreads();
  auto rd = [&](const u16* reg, int row, int ks) -> bf16x8 {
    return *(const bf16x8*)&reg[row * 64 + (((ks * 4 + kg) ^ (row & 7)) << 3)];
  };
  bf16x8 Cf[2][2];
  f32x4 accS[2][2];
#pragma unroll
  for (int m = 0; m < 2; ++m)
#pragma unroll
    for (int n = 0; n < 2; ++n) accS[m][n] = (f32x4){0.f, 0.f, 0.f, 0.f};
#pragma unroll
  for (int ks = 0; ks < 2; ++ks) {
    bf16x8 Bf[2];
#pragma unroll
    for (int m = 0; m < 2; ++m) Cf[m][ks] = rd(Cs, wm * 32 + m * 16 + li, ks);
#pragma unroll
    for (int n = 0; n < 2; ++n) Bf[n] = rd(Bs, wn * 32 + n * 16 + li, ks);
#pragma unroll
    for (int m = 0; m < 2; ++m)
#pragma unroll
      for (int n = 0; n < 2; ++n)
        accS[m][n] = __builtin_amdgcn_mfma_f32_16x16x32_bf16(Cf[m][ks], Bf[n], accS[m][n], 0, 0, 0);
  }
#pragma unroll
  for (int m = 0; m < 2; ++m)
#pragma unroll
    for (int n = 0; n < 2; ++n)
#pragma unroll
      for (int r = 0; r < 4; ++r) {
        int t = wm * 32 + m * 16 + kg * 4 + r;
        int s = wn * 32 + n * 16 + li;
        float f = (s <= t) ? expf(phiT[t] + eSs[s]) * dSs[s] : 0.f;
        Ps[t * 64 + (((s >> 3) ^ (t & 7)) << 3) + (s & 7)] = f2b(accS[m][n][r] * f);
      }
  __syncthreads();
  f32x4 accY[2][2], acc2[2][2];
#pragma unroll
  for (int m = 0; m < 2; ++m)
#pragma unroll
    for (int n = 0; n < 2; ++n) {
      accY[m][n] = (f32x4){0.f, 0.f, 0.f, 0.f};
      acc2[m][n] = (f32x4){0.f, 0.f, 0.f, 0.f};
    }
#pragma unroll
  for (int ks = 0; ks < 2; ++ks) {
    bf16x8 Pf[2], Xf[2];
#pragma unroll
    for (int m = 0; m < 2; ++m) Pf[m] = rd(Ps, wm * 32 + m * 16 + li, ks);
#pragma unroll
    for (int n = 0; n < 2; ++n) Xf[n] = rd(Xs, wn * 32 + n * 16 + li, ks);
#pragma unroll
    for (int m = 0; m < 2; ++m)
#pragma unroll
      for (int n = 0; n < 2; ++n)
        accY[m][n] = __builtin_amdgcn_mfma_f32_16x16x32_bf16(Pf[m], Xf[n], accY[m][n], 0, 0, 0);
    if (k > 0) {
      bf16x8 Sf[2];
#pragma unroll
      for (int n = 0; n < 2; ++n) Sf[n] = rd(Ss, wn * 32 + n * 16 + li, ks);
#pragma unroll
      for (int m = 0; m < 2; ++m)
#pragma unroll
        for (int n = 0; n < 2; ++n)
          acc2[m][n] = __builtin_amdgcn_mfma_f32_16x16x32_bf16(Cf[m][ks], Sf[n], acc2[m][n], 0, 0, 0);
    }
  }
  float dp = Dp[h];
  float ls[8] = {};
#pragma unroll
  for (int m = 0; m < 2; ++m)
#pragma unroll
    for (int n = 0; n < 2; ++n)
#pragma unroll
      for (int r = 0; r < 4; ++r) {
        int t = wm * 32 + m * 16 + kg * 4 + r;
        int c = wn * 32 + n * 16 + li;
        float xv = b2f(Xs[c * 64 + (((t >> 3) ^ (c & 7)) << 3) + (t & 7)]);
        float val = accY[m][n][r] + eTs[t] * acc2[m][n][r] + dp * xv;
        ls[m * 4 + r] = fmaf(val, val, ls[m * 4 + r]);
        float z = proj[(size_t)(t0 + t) * NPROJ + OFF_Z + h * HDIM + zh * 64 + c];
        float sz = z / (1.f + expf(-z));
        Yh[(size_t)(t0 + t) * DINNER + h * HDIM + zh * 64 + c] = f2b(val * nws[c] * sz);
      }
#pragma unroll
  for (int j = 0; j < 8; ++j) {
    float v = ls[j];
    v += __shfl_xor(v, 1); v += __shfl_xor(v, 2);
    v += __shfl_xor(v, 4); v += __shfl_xor(v, 8);
    if (li == 0) atomicAdd(&sq[wm * 32 + (j >> 2) * 16 + kg * 4 + (j & 3)], v);
  }
  __syncthreads();
  if (tid < 64) atomicAdd(&rmsacc[t0 + tid], sq[tid]);
}

extern "C" void kernel_launch(void* const* d_in, const int* in_sizes, int n_in,
                              void* d_out, int out_size, void* d_ws, size_t ws_size,
                              hipStream_t stream) {
  const float* x       = (const float*)d_in[0];
  const float* W_in    = (const float*)d_in[1];
  const float* conv_w  = (const float*)d_in[2];
  const float* conv_b  = (const float*)d_in[3];
  const float* A_log   = (const float*)d_in[4];
  const float* Dp      = (const float*)d_in[5];
  const float* dt_bias = (const float*)d_in[6];
  const float* W_out   = (const float*)d_in[7];
  const float* norm_w  = (const float*)d_in[8];
  float* out = (float*)d_out;

  char* base = (char*)d_ws;
  size_t o = 0;
  auto alloc = [&](size_t bytes) { char* r = base + o; o += (bytes + 255) & ~(size_t)255; return r; };
  float* proj   = (float*)alloc((size_t)LSEQ * NPROJ * 4);
  float* Phi    = (float*)alloc((size_t)LSEQ * NH * 4);
  float* dts    = (float*)alloc((size_t)LSEQ * NH * 4);
  float* rmsacc = (float*)alloc((size_t)LSEQ * 4);
  u16*   Sloc   = (u16*)alloc((size_t)16 * NH * 8192 * 2);
  u16*   xactT  = (u16*)alloc((size_t)16 * NH * 8192 * 2);
  u16*   Ah     = (u16*)alloc((size_t)LSEQ * 768 * 2);
  u16*   Wh     = (u16*)alloc((size_t)NPADW * 768 * 2);
  u16*   Woh    = (u16*)alloc((size_t)768 * DINNER * 2);
  u16*   Yh     = (u16*)alloc((size_t)LSEQ * DINNER * 2);
  float* Pp     = (float*)alloc((size_t)4 * LSEQ * 768 * 4);

  ksplit_all<<<dim3((S0N + S1N) / 256), 256, 0, stream>>>(x, W_in, Ah, Wh);
  gemm1<64, 128, 0, true><<<dim3(640), 256, 0, stream>>>(
      Ah, Wh, proj, 768, 768, 768, NPROJ, NPROJ);
  conv_state<<<dim3(16, NH), 256, 0, stream>>>(
      proj, conv_w, conv_b, A_log, dt_bias, xactT, Sloc, Phi, dts, rmsacc);
  chunk_scan<<<dim3(NH * 32), 256, 0, stream>>>(Sloc, Phi, W_out, Woh);
  ssm_out<<<dim3(16, NH, 2), 256, 0, stream>>>(
      proj, xactT, Phi, dts, Dp, Sloc, norm_w, Yh, rmsacc);
  gemm1<64, 64, 1, false><<<dim3(768), 256, 0, stream>>>(
      Yh, Woh, Pp, 1536, 1536, 384, 768, 768);
  addk<<<dim3(LSEQ * 768 / 4 / 256), 256, 0, stream>>>(Pp, rmsacc, out);
}